// Round 2
// baseline (215.518 us; speedup 1.0000x reference)
//
#include <hip/hip_runtime.h>
#include <hip/hip_bf16.h>
#include <math.h>

// Problem constants
#define B_ 64
#define T_ 500
#define NLOGIT 13          // 2*MAX_TAU+1
#define TR_ 5              // tracks
#define NP_ 6              // NTDOAS (mic pairs)
#define NCLS_ 13
#define NCELLS (B_ * T_)   // 32000
#define CELLS_PER_BLOCK 32
#define NBLOCKS (NCELLS / CELLS_PER_BLOCK)   // 1000
#define THREADS (CELLS_PER_BLOCK * NP_)      // 192
#define PRED_PER_CELL (NLOGIT * TR_ * NP_)   // 390
#define PRED_PER_BLOCK (CELLS_PER_BLOCK * PRED_PER_CELL) // 12480
#define TGT_PER_CELL (TR_ * 5 * NCLS_)       // 325
#define NTOTAL (NCELLS * NP_)                // 192000 "n" rows
#define IGNORE_ (-100)

// ---- lexicographic permutation table (matches itertools.permutations) ----
struct PermTable { int p[120][5]; };
constexpr PermTable make_perms() {
    PermTable t{};
    for (int i = 0; i < 120; ++i) {
        int avail[5] = {0, 1, 2, 3, 4};
        int rem = i;
        const int f[5] = {24, 6, 2, 1, 1};
        for (int k = 0; k < 5; ++k) {
            int d = rem / f[k];
            rem = rem % f[k];
            t.p[i][k] = avail[d];
            for (int m = d; m < 4 - k; ++m) avail[m] = avail[m + 1];
        }
    }
    return t;
}
__device__ constexpr PermTable PT = make_perms();

// Scan one cell's 65 (track,class) entries in flat order tr*13+c, pick the
// first <=5 active, compute their 6 TDOA classes; fill rest with IGNORE.
__device__ inline void scan_targets(const float* __restrict__ tg,
                                    const float* __restrict__ mic,
                                    int* __restrict__ cls_out /* [5][6] */) {
    float mx[4], my[4], mz[4];
#pragma unroll
    for (int m = 0; m < 4; ++m) {
        mx[m] = mic[m * 3 + 0];
        my[m] = mic[m * 3 + 1];
        mz[m] = mic[m * 3 + 2];
    }
    int nsel = 0;
    for (int tr = 0; tr < TR_; ++tr) {
        const float* row = tg + tr * 65;  // (5 ch x 13 cls), ch stride 13
        for (int c = 0; c < NCLS_; ++c) {
            if (nsel >= 5) break;
            float act = row[c];  // channel 0 = active flag (0.0 or 1.0)
            if (act != 0.0f) {
                float dist = row[52 + c];          // channel 4
                float sx = row[13 + c] * dist;     // doa * dist
                float sy = row[26 + c] * dist;
                float sz = row[39 + c] * dist;
                float d[4];
#pragma unroll
                for (int m = 0; m < 4; ++m) {
                    float dx = sx - mx[m], dy = sy - my[m], dz = sz - mz[m];
                    d[m] = sqrtf(dx * dx + dy * dy + dz * dz);
                }
                const int Q0[6] = {0, 0, 0, 1, 1, 2};
                const int Q1[6] = {1, 2, 3, 2, 3, 3};
#pragma unroll
                for (int q = 0; q < 6; ++q) {
                    float td = d[Q0[q]] - d[Q1[q]];
                    float v = td * 24000.0f / 343.0f;
                    int cls = (int)rintf(v) + 6;   // MAX_TAU = 6
                    cls_out[nsel * 6 + q] = cls;
                }
                ++nsel;
            }
        }
    }
    for (; nsel < 5; ++nsel) {
#pragma unroll
        for (int q = 0; q < 6; ++q) cls_out[nsel * 6 + q] = IGNORE_;
    }
}

__global__ __launch_bounds__(THREADS) void tdoa_main(
        const float* __restrict__ pred, const float* __restrict__ target,
        const float* __restrict__ mic,
        float* __restrict__ costp, int* __restrict__ vpp, int* __restrict__ crp) {
    __shared__ float sp[PRED_PER_BLOCK];                 // 49920 B
    __shared__ int scls[CELLS_PER_BLOCK * 5 * NP_];      // 3840 B
    __shared__ float sredf[3];
    __shared__ int sredv[3], sredc[3];

    const int j = threadIdx.x;
    const int blk = blockIdx.x;

    // --- stage this block's 32 cells of pred into LDS, coalesced float4 ---
    {
        const float4* p4 = (const float4*)(pred + (size_t)blk * PRED_PER_BLOCK);
        float4* s4 = (float4*)sp;
        for (int i = j; i < PRED_PER_BLOCK / 4; i += THREADS) s4[i] = p4[i];
    }
    // --- 32 scanner threads (one per cell), spread across all 3 waves ---
    if (j % NP_ == 0) {
        int cl = j / NP_;
        int cell = blk * CELLS_PER_BLOCK + cl;
        scan_targets(target + (size_t)cell * TGT_PER_CELL, mic, &scls[cl * 30]);
    }
    __syncthreads();

    const int cellL = j / NP_;
    const int p = j % NP_;
    const float* L = sp + cellL * PRED_PER_CELL;  // l[cl][tr][p] at cl*30+tr*6+p

    // --- per-track log-softmax pieces + argmax over the 13 classes ---
    float maxv[5], logZ[5];
    int amax[5];
#pragma unroll
    for (int tr = 0; tr < TR_; ++tr) {
        float m = L[0 * 30 + tr * 6 + p];
        int am = 0;
#pragma unroll
        for (int cl = 1; cl < NLOGIT; ++cl) {
            float v = L[cl * 30 + tr * 6 + p];
            if (v > m) { m = v; am = cl; }   // strict > keeps first occurrence
        }
        float s = 0.0f;
#pragma unroll
        for (int cl = 0; cl < NLOGIT; ++cl) s += expf(L[cl * 30 + tr * 6 + p] - m);
        maxv[tr] = m;
        logZ[tr] = logf(s);
        amax[tr] = am;
    }

    // --- loss matrix lm[slot][track] = valid ? -logp[tgt][tr] : 0 ---
    float lm[5][5];
#pragma unroll
    for (int slot = 0; slot < 5; ++slot) {
        int tc = scls[cellL * 30 + slot * 6 + p];
        if (tc == IGNORE_) {
#pragma unroll
            for (int tr = 0; tr < TR_; ++tr) lm[slot][tr] = 0.0f;
        } else {
            int tcc = min(max(tc, 0), NLOGIT - 1);
#pragma unroll
            for (int tr = 0; tr < TR_; ++tr)
                lm[slot][tr] = logZ[tr] - (L[tcc * 30 + tr * 6 + p] - maxv[tr]);
        }
    }

    // --- brute-force 120 permutations, fully unrolled (static indices) ---
    float best = 1e30f;
    int bi = 0;
#pragma unroll
    for (int i = 0; i < 120; ++i) {
        float c = lm[0][PT.p[i][0]];
        c += lm[1][PT.p[i][1]];
        c += lm[2][PT.p[i][2]];
        c += lm[3][PT.p[i][3]];
        c += lm[4][PT.p[i][4]];
        if (c < best) { best = c; bi = i; }  // strict < keeps first min
    }
    float mycost = best / 5.0f;

    // --- accuracy counts: tgt_perm[k] = tgt[best_perm[k]] ---
    int vp = 0, cr = 0;
#pragma unroll
    for (int k = 0; k < 5; ++k) {
        int slot = PT.p[bi][k];                      // runtime row, const mem
        int tc = scls[cellL * 30 + slot * 6 + p];    // LDS dynamic index: OK
        if (tc != IGNORE_) {
            ++vp;
            if (amax[k] == tc) ++cr;
        }
    }

    // --- block reduction: wave shfl, then 3 wave partials via LDS ---
    float rc = mycost;
    int rv = vp, rr = cr;
#pragma unroll
    for (int off = 32; off > 0; off >>= 1) {
        rc += __shfl_down(rc, off, 64);
        rv += __shfl_down(rv, off, 64);
        rr += __shfl_down(rr, off, 64);
    }
    int wave = j >> 6, lane = j & 63;
    if (lane == 0) { sredf[wave] = rc; sredv[wave] = rv; sredc[wave] = rr; }
    __syncthreads();
    if (j == 0) {
        costp[blk] = sredf[0] + sredf[1] + sredf[2];
        vpp[blk]   = sredv[0] + sredv[1] + sredv[2];
        crp[blk]   = sredc[0] + sredc[1] + sredc[2];
    }
}

__global__ __launch_bounds__(256) void tdoa_final(
        const float* __restrict__ costp, const int* __restrict__ vpp,
        const int* __restrict__ crp, float* __restrict__ out) {
    __shared__ float sf[4];
    __shared__ int sv[4], sc[4];
    int j = threadIdx.x;
    float c = 0.0f;
    int v = 0, r = 0;
    for (int i = j; i < NBLOCKS; i += 256) {
        c += costp[i];
        v += vpp[i];
        r += crp[i];
    }
#pragma unroll
    for (int off = 32; off > 0; off >>= 1) {
        c += __shfl_down(c, off, 64);
        v += __shfl_down(v, off, 64);
        r += __shfl_down(r, off, 64);
    }
    int wave = j >> 6, lane = j & 63;
    if (lane == 0) { sf[wave] = c; sv[wave] = v; sc[wave] = r; }
    __syncthreads();
    if (j == 0) {
        float tc = sf[0] + sf[1] + sf[2] + sf[3];
        int tv = sv[0] + sv[1] + sv[2] + sv[3];
        int trr = sc[0] + sc[1] + sc[2] + sc[3];
        out[0] = tc / (float)NTOTAL;                           // loss
        out[1] = (tv > 0) ? ((float)trr / (float)tv) : 0.0f;   // acc
    }
}

extern "C" void kernel_launch(void* const* d_in, const int* in_sizes, int n_in,
                              void* d_out, int out_size, void* d_ws, size_t ws_size,
                              hipStream_t stream) {
    const float* pred   = (const float*)d_in[0];
    const float* target = (const float*)d_in[1];
    const float* mic    = (const float*)d_in[2];
    float* out = (float*)d_out;

    float* costp = (float*)d_ws;
    int*   vpp   = (int*)((char*)d_ws + NBLOCKS * sizeof(float));
    int*   crp   = (int*)((char*)d_ws + 2 * NBLOCKS * sizeof(float));

    tdoa_main<<<NBLOCKS, THREADS, 0, stream>>>(pred, target, mic, costp, vpp, crp);
    tdoa_final<<<1, 256, 0, stream>>>(costp, vpp, crp, out);
}

// Round 7
// 143.207 us; speedup vs baseline: 1.5049x; 1.5049x over previous
//
#include <hip/hip_runtime.h>
#include <hip/hip_bf16.h>
#include <math.h>

#define NCELLS 32000           // B*T
#define NP_ 6                  // mic pairs
#define IGN (-100)
#define MAIN_BLOCKS 750        // 192000 threads / 256
#define SCLS_BYTES ((size_t)NCELLS * NP_ * 8)

// ---- lexicographic permutation table (matches itertools.permutations) ----
struct PermTable { int p[120][5]; };
constexpr PermTable make_perms() {
    PermTable t{};
    for (int i = 0; i < 120; ++i) {
        int avail[5] = {0, 1, 2, 3, 4};
        int rem = i;
        const int f[5] = {24, 6, 2, 1, 1};
        for (int k = 0; k < 5; ++k) {
            int d = rem / f[k];
            rem = rem % f[k];
            t.p[i][k] = avail[d];
            for (int m = d; m < 4 - k; ++m) avail[m] = avail[m + 1];
        }
    }
    return t;
}
__device__ constexpr PermTable PT = make_perms();

// ---------------------------------------------------------------------------
// Kernel A: one thread per (cell, track). Rank actives across tracks via a
// small LDS prefix (flat order = track-major, matching argsort(!act, stable)),
// compute 6 TDOA classes for slots < 5, write packed int8 scls[cell][p][slot].
// ---------------------------------------------------------------------------
__global__ __launch_bounds__(320) void tdoa_scan(
        const float* __restrict__ target, const float* __restrict__ mic,
        char* __restrict__ scls) {
    __shared__ int cnt[64][5];
    const int j = threadIdx.x;
    const int cellL = j / 5, tr = j - cellL * 5;
    const int cell = blockIdx.x * 64 + cellL;
    const float* __restrict__ tg = target + (size_t)cell * 325 + tr * 65;

    float fl[13];
#pragma unroll
    for (int c = 0; c < 13; ++c) fl[c] = tg[c];   // active channel
    int mycnt = 0;
#pragma unroll
    for (int c = 0; c < 13; ++c) mycnt += (fl[c] != 0.0f) ? 1 : 0;
    cnt[cellL][tr] = mycnt;
    __syncthreads();

    int base = 0, total = 0;
#pragma unroll
    for (int t = 0; t < 5; ++t) {
        int v = cnt[cellL][t];
        total += v;
        if (t < tr) base += v;
    }

    char* __restrict__ dst = scls + (size_t)cell * 48;  // 6 pairs x 8 bytes
    if (tr == 0) {   // fill unused slots with IGNORE (ws is poisoned 0xAA)
        for (int s = (total < 5 ? total : 5); s < 5; ++s)
#pragma unroll
            for (int p = 0; p < 6; ++p) dst[p * 8 + s] = (char)IGN;
    }

    float mx[4], my[4], mz[4];
#pragma unroll
    for (int m = 0; m < 4; ++m) {
        mx[m] = mic[m * 3 + 0];
        my[m] = mic[m * 3 + 1];
        mz[m] = mic[m * 3 + 2];
    }

    int slot = base;
#pragma unroll
    for (int c = 0; c < 13; ++c) {
        if (fl[c] != 0.0f) {
            if (slot < 5) {
                float dist = tg[52 + c];              // channel 4
                float sx = tg[13 + c] * dist;         // doa * dist
                float sy = tg[26 + c] * dist;
                float sz = tg[39 + c] * dist;
                float d[4];
#pragma unroll
                for (int m = 0; m < 4; ++m) {
                    float dx = sx - mx[m], dy = sy - my[m], dz = sz - mz[m];
                    d[m] = sqrtf(dx * dx + dy * dy + dz * dz);
                }
                const int Q0[6] = {0, 0, 0, 1, 1, 2};
                const int Q1[6] = {1, 2, 3, 2, 3, 3};
#pragma unroll
                for (int q = 0; q < 6; ++q) {
                    float td = (d[Q0[q]] - d[Q1[q]]) * (24000.0f / 343.0f);
                    int cls = (int)rintf(td) + 6;     // MAX_TAU = 6
                    cls = cls < 0 ? 0 : (cls > 12 ? 12 : cls);
                    dst[q * 8 + slot] = (char)cls;
                }
            }
            ++slot;
        }
    }
}

// ---------------------------------------------------------------------------
// Kernel B: one thread per (cell, pair). Direct global loads (wave footprint
// 16.6 KB fits L1), register-only lm[5][5], fully unrolled 120-perm scan.
// ---------------------------------------------------------------------------
__global__ __launch_bounds__(256, 4) void tdoa_main(
        const float* __restrict__ pred, const char* __restrict__ scls,
        float* __restrict__ costp, int* __restrict__ vpp, int* __restrict__ crp) {
    const int tid = blockIdx.x * 256 + threadIdx.x;   // exactly 192000 threads
    const int cell = tid / 6, p = tid - cell * 6;
    const float* __restrict__ L = pred + (size_t)cell * 390 + p;

    const unsigned long long su =
        *(const unsigned long long*)(scls + (size_t)tid * 8);

    float lse[5];
    int amax[5];
#pragma unroll
    for (int tr = 0; tr < 5; ++tr) {
        float v[13];
#pragma unroll
        for (int c = 0; c < 13; ++c) v[c] = L[c * 30 + tr * 6];
        float m = v[0];
        int am = 0;
#pragma unroll
        for (int c = 1; c < 13; ++c) {
            if (v[c] > m) { m = v[c]; am = c; }   // strict > = first occurrence
        }
        float s = 0.0f;
#pragma unroll
        for (int c = 0; c < 13; ++c) s += __expf(v[c] - m);
        lse[tr] = m + __logf(s);
        amax[tr] = am;
    }

    float lm[5][5];
#pragma unroll
    for (int slot = 0; slot < 5; ++slot) {
        int tcs = (int)(char)((su >> (slot * 8)) & 0xffULL);
        bool val = (tcs != IGN);
        int tcc = val ? tcs : 0;
        tcc = min(max(tcc, 0), 12);
#pragma unroll
        for (int tr = 0; tr < 5; ++tr) {
            float g = L[tcc * 30 + tr * 6];           // L1 hit (same lines)
            lm[slot][tr] = val ? (lse[tr] - g) : 0.0f;
        }
    }

    float best = 1e30f;
    int bi = 0;
#pragma unroll
    for (int i = 0; i < 120; ++i) {
        float c = lm[0][PT.p[i][0]] + lm[1][PT.p[i][1]] + lm[2][PT.p[i][2]]
                + lm[3][PT.p[i][3]] + lm[4][PT.p[i][4]];
        if (c < best) { best = c; bi = i; }           // strict < = first min
    }
    float mycost = best * (1.0f / 5.0f);

    int vp = 0, cr = 0;
#pragma unroll
    for (int k = 0; k < 5; ++k) {
        int slot = PT.p[bi][k];                       // rodata load, L1 hit
        int tcs = (int)(char)((su >> (slot * 8)) & 0xffULL);
        if (tcs != IGN) {
            ++vp;
            if (amax[k] == tcs) ++cr;
        }
    }

    // block reduction: wave shfl, then 4 wave partials via LDS
    float rc = mycost;
    int rv = vp, rr = cr;
#pragma unroll
    for (int off = 32; off > 0; off >>= 1) {
        rc += __shfl_down(rc, off, 64);
        rv += __shfl_down(rv, off, 64);
        rr += __shfl_down(rr, off, 64);
    }
    __shared__ float sf[4];
    __shared__ int sv[4], sc2[4];
    const int wave = threadIdx.x >> 6, lane = threadIdx.x & 63;
    if (lane == 0) { sf[wave] = rc; sv[wave] = rv; sc2[wave] = rr; }
    __syncthreads();
    if (threadIdx.x == 0) {
        costp[blockIdx.x] = sf[0] + sf[1] + sf[2] + sf[3];
        vpp[blockIdx.x]   = sv[0] + sv[1] + sv[2] + sv[3];
        crp[blockIdx.x]   = sc2[0] + sc2[1] + sc2[2] + sc2[3];
    }
}

__global__ __launch_bounds__(256) void tdoa_final(
        const float* __restrict__ costp, const int* __restrict__ vpp,
        const int* __restrict__ crp, float* __restrict__ out) {
    __shared__ float sf[4];
    __shared__ int sv[4], sc[4];
    int j = threadIdx.x;
    float c = 0.0f;
    int v = 0, r = 0;
    for (int i = j; i < MAIN_BLOCKS; i += 256) {
        c += costp[i];
        v += vpp[i];
        r += crp[i];
    }
#pragma unroll
    for (int off = 32; off > 0; off >>= 1) {
        c += __shfl_down(c, off, 64);
        v += __shfl_down(v, off, 64);
        r += __shfl_down(r, off, 64);
    }
    int wave = j >> 6, lane = j & 63;
    if (lane == 0) { sf[wave] = c; sv[wave] = v; sc[wave] = r; }
    __syncthreads();
    if (j == 0) {
        float tc = sf[0] + sf[1] + sf[2] + sf[3];
        int tv = sv[0] + sv[1] + sv[2] + sv[3];
        int trr = sc[0] + sc[1] + sc[2] + sc[3];
        out[0] = tc / (float)(NCELLS * NP_);                   // loss
        out[1] = (tv > 0) ? ((float)trr / (float)tv) : 0.0f;   // acc
    }
}

extern "C" void kernel_launch(void* const* d_in, const int* in_sizes, int n_in,
                              void* d_out, int out_size, void* d_ws, size_t ws_size,
                              hipStream_t stream) {
    const float* pred   = (const float*)d_in[0];
    const float* target = (const float*)d_in[1];
    const float* mic    = (const float*)d_in[2];
    float* out = (float*)d_out;

    char*  scls  = (char*)d_ws;
    float* costp = (float*)((char*)d_ws + SCLS_BYTES);
    int*   vpp   = (int*)((char*)d_ws + SCLS_BYTES + MAIN_BLOCKS * 4);
    int*   crp   = (int*)((char*)d_ws + SCLS_BYTES + MAIN_BLOCKS * 8);

    tdoa_scan<<<NCELLS / 64, 320, 0, stream>>>(target, mic, scls);
    tdoa_main<<<MAIN_BLOCKS, 256, 0, stream>>>(pred, scls, costp, vpp, crp);
    tdoa_final<<<1, 256, 0, stream>>>(costp, vpp, crp, out);
}

// Round 8
// 135.520 us; speedup vs baseline: 1.5903x; 1.0567x over previous
//
#include <hip/hip_runtime.h>
#include <hip/hip_bf16.h>
#include <math.h>

#define NCELLS 32000           // B*T
#define NP_ 6                  // mic pairs
#define IGN (-100)
#define CPB 64                 // cells per block
#define NBLK (NCELLS / CPB)    // 500
#define THREADS 384            // 64 cells x 6 pairs

// ---- lexicographic permutation table (matches itertools.permutations) ----
struct PermTable { int p[120][5]; };
constexpr PermTable make_perms() {
    PermTable t{};
    for (int i = 0; i < 120; ++i) {
        int avail[5] = {0, 1, 2, 3, 4};
        int rem = i;
        const int f[5] = {24, 6, 2, 1, 1};
        for (int k = 0; k < 5; ++k) {
            int d = rem / f[k];
            rem = rem % f[k];
            t.p[i][k] = avail[d];
            for (int m = d; m < 4 - k; ++m) avail[m] = avail[m + 1];
        }
    }
    return t;
}
__device__ constexpr PermTable PT = make_perms();

// ---------------------------------------------------------------------------
// Fused kernel: phase 1 (320 threads) = per-(cell,track) target scan with
// LDS rank-prefix -> classes into LDS. phase 2 (384 threads) = per-(cell,pair)
// softmax + 120-perm assignment + accuracy. Per-block partials to ws.
// ---------------------------------------------------------------------------
__global__ __launch_bounds__(THREADS) void tdoa_fused(
        const float* __restrict__ pred, const float* __restrict__ target,
        const float* __restrict__ mic,
        float* __restrict__ costp, int* __restrict__ vpp, int* __restrict__ crp) {
    __shared__ int cnt[CPB][5];
    __shared__ int scls[CPB][NP_][5];      // 7680 B
    const int j = threadIdx.x;
    const int blk = blockIdx.x;

    // ---------------- phase 1: target scan (threads 0..319) ----------------
    if (j < CPB * 5) {
        const int cellL = j / 5, tr = j - cellL * 5;
        const int cell = blk * CPB + cellL;
        const float* __restrict__ tg = target + (size_t)cell * 325 + tr * 65;

        float fl[13];
#pragma unroll
        for (int c = 0; c < 13; ++c) fl[c] = tg[c];   // active channel
        int mycnt = 0;
#pragma unroll
        for (int c = 0; c < 13; ++c) mycnt += (fl[c] != 0.0f) ? 1 : 0;
        cnt[cellL][tr] = mycnt;
        __syncthreads();

        int base = 0, total = 0;
#pragma unroll
        for (int t = 0; t < 5; ++t) {
            int v = cnt[cellL][t];
            total += v;
            if (t < tr) base += v;
        }

        if (tr == 0) {   // fill unused slots with IGNORE
            for (int s = (total < 5 ? total : 5); s < 5; ++s)
#pragma unroll
                for (int p = 0; p < 6; ++p) scls[cellL][p][s] = IGN;
        }

        float mx[4], my[4], mz[4];
#pragma unroll
        for (int m = 0; m < 4; ++m) {
            mx[m] = mic[m * 3 + 0];
            my[m] = mic[m * 3 + 1];
            mz[m] = mic[m * 3 + 2];
        }

        int slot = base;
#pragma unroll
        for (int c = 0; c < 13; ++c) {
            if (fl[c] != 0.0f) {
                if (slot < 5) {
                    float dist = tg[52 + c];              // channel 4
                    float sx = tg[13 + c] * dist;         // doa * dist
                    float sy = tg[26 + c] * dist;
                    float sz = tg[39 + c] * dist;
                    float d[4];
#pragma unroll
                    for (int m = 0; m < 4; ++m) {
                        float dx = sx - mx[m], dy = sy - my[m], dz = sz - mz[m];
                        d[m] = sqrtf(dx * dx + dy * dy + dz * dz);
                    }
                    const int Q0[6] = {0, 0, 0, 1, 1, 2};
                    const int Q1[6] = {1, 2, 3, 2, 3, 3};
#pragma unroll
                    for (int q = 0; q < 6; ++q) {
                        float td = (d[Q0[q]] - d[Q1[q]]) * (24000.0f / 343.0f);
                        int cls = (int)rintf(td) + 6;     // MAX_TAU = 6
                        cls = cls < 0 ? 0 : (cls > 12 ? 12 : cls);
                        scls[cellL][q][slot] = cls;
                    }
                }
                ++slot;
            }
        }
    } else {
        __syncthreads();   // match phase-1 barrier (uniform control flow per block)
    }
    __syncthreads();

    // ---------------- phase 2: per-(cell,pair) loss ----------------
    const int cellL = j / NP_, p = j - cellL * NP_;
    const float* __restrict__ L =
        pred + (size_t)(blk * CPB + cellL) * 390 + p;

    float lse[5];
    int amax[5];
#pragma unroll
    for (int tr = 0; tr < 5; ++tr) {
        float v[13];
#pragma unroll
        for (int c = 0; c < 13; ++c) v[c] = L[c * 30 + tr * 6];
        float m = v[0];
        int am = 0;
#pragma unroll
        for (int c = 1; c < 13; ++c) {
            if (v[c] > m) { m = v[c]; am = c; }   // strict > = first occurrence
        }
        float s = 0.0f;
#pragma unroll
        for (int c = 0; c < 13; ++c) s += __expf(v[c] - m);
        lse[tr] = m + __logf(s);
        amax[tr] = am;
    }

    int tcs[5];
#pragma unroll
    for (int slot = 0; slot < 5; ++slot) tcs[slot] = scls[cellL][p][slot];

    float lm[5][5];
#pragma unroll
    for (int slot = 0; slot < 5; ++slot) {
        bool val = (tcs[slot] != IGN);
        int tcc = val ? tcs[slot] : 0;
        tcc = min(max(tcc, 0), 12);
#pragma unroll
        for (int tr = 0; tr < 5; ++tr) {
            float g = L[tcc * 30 + tr * 6];           // L1 hit (same lines)
            lm[slot][tr] = val ? (lse[tr] - g) : 0.0f;
        }
    }

    float best = 1e30f;
    int bi = 0;
#pragma unroll
    for (int i = 0; i < 120; ++i) {
        float c = lm[0][PT.p[i][0]] + lm[1][PT.p[i][1]] + lm[2][PT.p[i][2]]
                + lm[3][PT.p[i][3]] + lm[4][PT.p[i][4]];
        if (c < best) { best = c; bi = i; }           // strict < = first min
    }
    float mycost = best * (1.0f / 5.0f);

    int vp = 0, cr = 0;
#pragma unroll
    for (int k = 0; k < 5; ++k) {
        int slot = PT.p[bi][k];                       // rodata, L1 hit
        int tc = tcs[slot];
        if (tc != IGN) {
            ++vp;
            if (amax[k] == tc) ++cr;
        }
    }

    // block reduction: wave shfl, then 6 wave partials via LDS
    float rc = mycost;
    int rv = vp, rr = cr;
#pragma unroll
    for (int off = 32; off > 0; off >>= 1) {
        rc += __shfl_down(rc, off, 64);
        rv += __shfl_down(rv, off, 64);
        rr += __shfl_down(rr, off, 64);
    }
    __shared__ float sf[6];
    __shared__ int sv[6], sc2[6];
    const int wave = j >> 6, lane = j & 63;
    if (lane == 0) { sf[wave] = rc; sv[wave] = rv; sc2[wave] = rr; }
    __syncthreads();
    if (j == 0) {
        float c = 0.0f;
        int v = 0, r = 0;
#pragma unroll
        for (int w = 0; w < 6; ++w) { c += sf[w]; v += sv[w]; r += sc2[w]; }
        costp[blk] = c;
        vpp[blk] = v;
        crp[blk] = r;
    }
}

__global__ __launch_bounds__(256) void tdoa_final(
        const float* __restrict__ costp, const int* __restrict__ vpp,
        const int* __restrict__ crp, float* __restrict__ out) {
    __shared__ float sf[4];
    __shared__ int sv[4], sc[4];
    int j = threadIdx.x;
    float c = 0.0f;
    int v = 0, r = 0;
    for (int i = j; i < NBLK; i += 256) {
        c += costp[i];
        v += vpp[i];
        r += crp[i];
    }
#pragma unroll
    for (int off = 32; off > 0; off >>= 1) {
        c += __shfl_down(c, off, 64);
        v += __shfl_down(v, off, 64);
        r += __shfl_down(r, off, 64);
    }
    int wave = j >> 6, lane = j & 63;
    if (lane == 0) { sf[wave] = c; sv[wave] = v; sc[wave] = r; }
    __syncthreads();
    if (j == 0) {
        float tc = sf[0] + sf[1] + sf[2] + sf[3];
        int tv = sv[0] + sv[1] + sv[2] + sv[3];
        int trr = sc[0] + sc[1] + sc[2] + sc[3];
        out[0] = tc / (float)(NCELLS * NP_);                   // loss
        out[1] = (tv > 0) ? ((float)trr / (float)tv) : 0.0f;   // acc
    }
}

extern "C" void kernel_launch(void* const* d_in, const int* in_sizes, int n_in,
                              void* d_out, int out_size, void* d_ws, size_t ws_size,
                              hipStream_t stream) {
    const float* pred   = (const float*)d_in[0];
    const float* target = (const float*)d_in[1];
    const float* mic    = (const float*)d_in[2];
    float* out = (float*)d_out;

    float* costp = (float*)d_ws;
    int*   vpp   = (int*)((char*)d_ws + NBLK * 4);
    int*   crp   = (int*)((char*)d_ws + NBLK * 8);

    tdoa_fused<<<NBLK, THREADS, 0, stream>>>(pred, target, mic, costp, vpp, crp);
    tdoa_final<<<1, 256, 0, stream>>>(costp, vpp, crp, out);
}